// Round 10
// baseline (924.075 us; speedup 1.0000x reference)
//
#include <hip/hip_runtime.h>
#include <math.h>

#define Nn 16384
#define Dd 128
#define Kk 32
#define JSPLIT 8
#define JCH (Nn / JSPLIT)     // 2048 j per chunk
#define NG (JCH / 16)         // 128 groups of 16 j per chunk
#define CAP 48                // cand slots per (row, chunk); mean count ~16 (8 sigma)
#define BAND 0.4f             // 2x bound on hi-bf16 approx rv error (validated r4-r9)
#define ZQ 2.4176f            // Phi^-1(1/128): expected ~128 candidates/row total

typedef unsigned short u16;
typedef short short8 __attribute__((ext_vector_type(8)));
typedef float f32x4 __attribute__((ext_vector_type(4)));

__device__ __forceinline__ u16 f2bf(float x) {
    unsigned u = __float_as_uint(x);
    unsigned r = u + 0x7FFFu + ((u >> 16) & 1u);   // RN-even
    return (u16)(r >> 16);
}

// --------------- prep: bf16 convert + sqn + analytic threshold + flag=0 ----
__global__ __launch_bounds__(256) void prep_kernel(const float* __restrict__ X,
                                                   u16* __restrict__ Xhi,
                                                   float* __restrict__ sqn,
                                                   float* __restrict__ thrA,
                                                   int* __restrict__ flagCnt) {
    const int i = blockIdx.x * 4 + (threadIdx.x >> 6);
    const int lane = threadIdx.x & 63;
    const float2 v = *(const float2*)(X + (size_t)i * Dd + lane * 2);
    const unsigned pack = ((unsigned)f2bf(v.y) << 16) | (unsigned)f2bf(v.x);
    *(unsigned*)(Xhi + (size_t)i * Dd + lane * 2) = pack;
    float s = fmaf(v.x, v.x, v.y * v.y);
#pragma unroll
    for (int o = 32; o > 0; o >>= 1) s += __shfl_down(s, o);
    if (lane == 0) {
        sqn[i] = s;
        // rv = sqn_j - 2 xi.xj ~ N(128, 256 + 4*sqn_i); keep rv < thr
        thrA[i] = 128.0f - ZQ * sqrtf(256.0f + 4.0f * s);
    }
    if (blockIdx.x == 0 && threadIdx.x == 0) *flagCnt = 0;
}

// ----------------------------------------------------------- knn filter ----
// 2048 blocks (256 i-tiles x 8 j-chunks) x 256 threads, LB(256,6) -> ~24
// waves/CU. Wave owns 16 i-rows (A-frag resident). B ping-pong buffered with
// UNCONDITIONAL distance-2 prefetch (Xhi/sqn padded). Static analytic
// thresholds: no reservoir, no compaction. Accepts appended to LDS
// (ds_write_b16 -> lgkmcnt queue, decoupled from the vmcnt load queue),
// flushed to global once at the end.
__global__ __launch_bounds__(256, 6) void knn_filter(const u16* __restrict__ Xhi,
                                                     const float* __restrict__ sqn,
                                                     const float* __restrict__ thrA,
                                                     u16* __restrict__ cand,
                                                     int* __restrict__ candCnt) {
    __shared__ u16 listS[64][CAP];   // 6 KB
    __shared__ int cntS[64];

    const int tid = threadIdx.x;
    const int wave = tid >> 6, lane = tid & 63;
    const int quad = lane >> 4, n16 = lane & 15;
    const int wave16 = wave * 16;
    const int itile = blockIdx.x >> 3, chunk = blockIdx.x & 7;
    const int ibase = itile * 64;
    const int jch0 = chunk * JCH;

    short8 aF[4];
    {
        const u16* arow = Xhi + (size_t)(ibase + wave16 + n16) * Dd + quad * 8;
#pragma unroll
        for (int ks = 0; ks < 4; ks++) aF[ks] = *(const short8*)(arow + ks * 32);
    }
    float rvThr[4];
    int cntReg[4] = {0, 0, 0, 0};
#pragma unroll
    for (int r = 0; r < 4; r++) rvThr[r] = thrA[ibase + wave16 + quad * 4 + r];

    const u16* bbase = Xhi + (size_t)(jch0 + n16) * Dd + quad * 8;
    short8 bb[2][4];
    float sj[2];
#pragma unroll
    for (int ks = 0; ks < 4; ks++) bb[0][ks] = *(const short8*)(bbase + ks * 32);
    sj[0] = sqn[jch0 + n16];
#pragma unroll
    for (int ks = 0; ks < 4; ks++) bb[1][ks] = *(const short8*)(bbase + 16 * Dd + ks * 32);
    sj[1] = sqn[jch0 + 16 + n16];

#define PROC(p, gg)                                                            \
    {                                                                          \
        f32x4 a01 = {0.f, 0.f, 0.f, 0.f}, a23 = {0.f, 0.f, 0.f, 0.f};          \
        a01 = __builtin_amdgcn_mfma_f32_16x16x32_bf16(aF[0], bb[p][0], a01, 0, 0, 0); \
        a23 = __builtin_amdgcn_mfma_f32_16x16x32_bf16(aF[2], bb[p][2], a23, 0, 0, 0); \
        a01 = __builtin_amdgcn_mfma_f32_16x16x32_bf16(aF[1], bb[p][1], a01, 0, 0, 0); \
        a23 = __builtin_amdgcn_mfma_f32_16x16x32_bf16(aF[3], bb[p][3], a23, 0, 0, 0); \
        const float sjc = sj[p];                                               \
        {   /* unconditional prefetch: Xhi/sqn padded past the chunk end */    \
            const u16* nb = bbase + (size_t)((gg) + 2) * 16 * Dd;              \
            bb[p][0] = *(const short8*)(nb);                                   \
            bb[p][1] = *(const short8*)(nb + 32);                              \
            bb[p][2] = *(const short8*)(nb + 64);                              \
            bb[p][3] = *(const short8*)(nb + 96);                              \
            sj[p] = sqn[jch0 + ((gg) + 2) * 16 + n16];                         \
        }                                                                      \
        const int jj = jch0 + (gg) * 16 + n16;                                 \
        float rv[4];                                                           \
        rv[0] = fmaf(-2.f, a01[0] + a23[0], sjc);                              \
        rv[1] = fmaf(-2.f, a01[1] + a23[1], sjc);                              \
        rv[2] = fmaf(-2.f, a01[2] + a23[2], sjc);                              \
        rv[3] = fmaf(-2.f, a01[3] + a23[3], sjc);                              \
        _Pragma("unroll")                                                      \
        for (int r = 0; r < 4; r++) {                                          \
            const unsigned long long mr = __ballot(rv[r] < rvThr[r]);          \
            const unsigned qm = (unsigned)((mr >> (quad * 16)) & 0xFFFFull);   \
            if (qm) {                                                          \
                if ((qm >> n16) & 1u) {                                        \
                    const int pos = cntReg[r] + __popc(qm & ((1u << n16) - 1u)); \
                    if (pos < CAP) listS[wave16 + quad * 4 + r][pos] = (u16)jj; \
                }                                                              \
                cntReg[r] += __popc(qm);                                       \
            }                                                                  \
        }                                                                      \
    }

    for (int g = 0; g < NG; g += 2) {
        PROC(0, g)
        PROC(1, g + 1)
    }
#undef PROC

    // flush: reg counts -> LDS (wave-local), then coalesced LDS -> global
    if (n16 == 0) {
#pragma unroll
        for (int r = 0; r < 4; r++) cntS[wave16 + quad * 4 + r] = cntReg[r];
    }
    for (int rl = 0; rl < 16; rl++) {
        const int row = wave16 + rl;
        const int n = cntS[row];            // same-wave LDS: no barrier needed
        const int gi = ibase + row;
        if (lane == 0) candCnt[(size_t)gi * JSPLIT + chunk] = n;  // raw (overflow signal)
        if (lane < min(n, CAP))
            cand[((size_t)gi * JSPLIT + chunk) * CAP + lane] = listS[row][lane];
    }
}

// ----------------------------------------------------------- knn exact -----
// 4096 blocks x 256 (wave = one row). Exact fp32 re-rank of the <=384-slot
// candidate union. VERIFIES sufficiency (>=32 exact values below thr-BAND,
// no overflow); failures flagged for knn_cleanup.
__global__ __launch_bounds__(256) void knn_exact(const float* __restrict__ X,
                                                 const float* __restrict__ sqn,
                                                 const float* __restrict__ thrA,
                                                 const u16* __restrict__ cand,
                                                 const int* __restrict__ candCnt,
                                                 int* __restrict__ idx_out,
                                                 int* __restrict__ flagCnt,
                                                 int* __restrict__ flagRows) {
    __shared__ float xiS[4][Dd];
    const int wave = threadIdx.x >> 6, lane = threadIdx.x & 63;
    const int i = blockIdx.x * 4 + wave;
    *(float2*)&xiS[wave][lane * 2] = *(const float2*)(X + (size_t)i * Dd + lane * 2);
    int cnts[JSPLIT], pre[JSPLIT];
    bool over = false;
    int M = 0;
#pragma unroll
    for (int k = 0; k < JSPLIT; k++) {
        int c = candCnt[(size_t)i * JSPLIT + k];
        over = over || (c > CAP);
        c = min(c, CAP);
        pre[k] = M; cnts[k] = c; M += c;
    }
    const float rvT = thrA[i];

    float rv[6];
    int jd[6];
#pragma unroll
    for (int s = 0; s < 6; s++) {
        const int slot = lane + 64 * s;
        rv[s] = INFINITY; jd[s] = -1;
        if (slot < M) {
            int k = 0;
#pragma unroll
            for (int q = 1; q < JSPLIT; q++) k += (slot >= pre[q] + cnts[q - 1] - cnts[q - 1] + (pre[q] ? 0 : 0), (slot >= pre[q]) ? 1 : 0);
            // (slot >= pre[q]) counts how many prefix starts are <= slot; adjust:
            k = 0;
#pragma unroll
            for (int q = 0; q < JSPLIT; q++) if (slot >= pre[q] + cnts[q]) k++;
            const int t = slot - pre[k];
            const int jj = cand[((size_t)i * JSPLIT + k) * CAP + t];
            const float* xj = X + (size_t)jj * Dd;
            float s0 = 0.f, s1 = 0.f, s2 = 0.f, s3 = 0.f;
#pragma unroll
            for (int d = 0; d < Dd; d += 4) {
                const float4 a = *(const float4*)&xiS[wave][d];
                const float4 b = *(const float4*)(xj + d);
                s0 = fmaf(a.x, b.x, s0); s1 = fmaf(a.y, b.y, s1);
                s2 = fmaf(a.z, b.z, s2); s3 = fmaf(a.w, b.w, s3);
            }
            rv[s] = fmaf(-2.f, (s0 + s1) + (s2 + s3), sqn[jj]);
            jd[s] = jj;
        }
    }
    int good = 0;
#pragma unroll
    for (int s = 0; s < 6; s++) good += __popcll(__ballot(rv[s] < rvT - BAND));
    if (over || good < Kk) {   // insufficient evidence -> exact cleanup path
        if (lane == 0) { const int f = atomicAdd(flagCnt, 1); flagRows[f] = i; }
        return;
    }
    int rk[6] = {0, 0, 0, 0, 0, 0};
    for (int s2 = 0; s2 < 64; s2++) {
        float ov[6];
#pragma unroll
        for (int s = 0; s < 6; s++) ov[s] = __shfl(rv[s], s2);
#pragma unroll
        for (int s = 0; s < 6; s++) {
            const int myid = lane + 64 * s;
#pragma unroll
            for (int t = 0; t < 6; t++)
                rk[s] += (ov[t] < rv[s] || (ov[t] == rv[s] && s2 + 64 * t < myid));
        }
    }
#pragma unroll
    for (int s = 0; s < 6; s++)
        if (jd[s] >= 0 && rk[s] < Kk) idx_out[(size_t)i * Kk + rk[s]] = jd[s];
}

// ----------------------------------------------------------- knn cleanup ---
// Exact fp32 full-scan top-32 for flagged rows (expected: none).
__global__ __launch_bounds__(256) void knn_cleanup(const float* __restrict__ X,
                                                   const float* __restrict__ sqn,
                                                   const int* __restrict__ flagCnt,
                                                   const int* __restrict__ flagRows,
                                                   float* __restrict__ scratch,
                                                   int* __restrict__ idx_out) {
    __shared__ float xi[Dd];
    __shared__ int cntS;
    __shared__ float lv[256];
    __shared__ int lj[256];
    const int tid = threadIdx.x;
    const int lane = tid & 63;
    const int F = *flagCnt;
    float* rvS = scratch + (size_t)blockIdx.x * Nn;
    for (int f = blockIdx.x; f < F; f += gridDim.x) {
        const int i = flagRows[f];
        __syncthreads();
        if (tid < Dd) xi[tid] = X[(size_t)i * Dd + tid];
        __syncthreads();
        for (int j = tid; j < Nn; j += 256) {
            const float* xj = X + (size_t)j * Dd;
            float s0 = 0.f, s1 = 0.f, s2 = 0.f, s3 = 0.f;
#pragma unroll
            for (int d = 0; d < Dd; d += 4) {
                const float4 a = *(const float4*)&xi[d];
                const float4 b = *(const float4*)(xj + d);
                s0 = fmaf(a.x, b.x, s0); s1 = fmaf(a.y, b.y, s1);
                s2 = fmaf(a.z, b.z, s2); s3 = fmaf(a.w, b.w, s3);
            }
            rvS[j] = fmaf(-2.f, (s0 + s1) + (s2 + s3), sqn[j]);
        }
        __syncthreads();
        float lo = -1.0e9f, hi = 1.0e9f, T = 1.0e9f;
        for (int it = 0; it < 48; it++) {
            const float mid = 0.5f * (lo + hi);
            int local = 0;
            for (int j = tid; j < Nn; j += 256) local += (rvS[j] < mid) ? 1 : 0;
#pragma unroll
            for (int o = 32; o > 0; o >>= 1) local += __shfl_down(local, o);
            __syncthreads();
            if (tid == 0) cntS = 0;
            __syncthreads();
            if (lane == 0) atomicAdd(&cntS, local);
            __syncthreads();
            const int c = cntS;
            if (c < Kk) lo = mid;
            else if (c > 200) hi = mid;
            else { T = mid; break; }
        }
        if (T == 1.0e9f) T = hi;
        __syncthreads();
        if (tid == 0) cntS = 0;
        __syncthreads();
        for (int j = tid; j < Nn; j += 256) {
            if (rvS[j] < T) {
                const int p = atomicAdd(&cntS, 1);
                if (p < 256) { lv[p] = rvS[j]; lj[p] = j; }
            }
        }
        __syncthreads();
        const int n = min(cntS, 256);
        if (tid < 64) {
            float v[4]; int jjj[4]; int rk2[4] = {0, 0, 0, 0};
#pragma unroll
            for (int s = 0; s < 4; s++) {
                const int sl = lane + 64 * s;
                v[s] = (sl < n) ? lv[sl] : INFINITY;
                jjj[s] = (sl < n) ? lj[sl] : -1;
            }
            for (int s2 = 0; s2 < 64; s2++) {
                const float o0 = __shfl(v[0], s2), o1 = __shfl(v[1], s2);
                const float o2 = __shfl(v[2], s2), o3 = __shfl(v[3], s2);
#pragma unroll
                for (int s = 0; s < 4; s++) {
                    const int myid = lane + 64 * s;
                    rk2[s] += (o0 < v[s] || (o0 == v[s] && s2 < myid));
                    rk2[s] += (o1 < v[s] || (o1 == v[s] && s2 + 64 < myid));
                    rk2[s] += (o2 < v[s] || (o2 == v[s] && s2 + 128 < myid));
                    rk2[s] += (o3 < v[s] || (o3 == v[s] && s2 + 192 < myid));
                }
            }
#pragma unroll
            for (int s = 0; s < 4; s++)
                if (jjj[s] >= 0 && rk2[s] < Kk) idx_out[(size_t)i * Kk + rk2[s]] = jjj[s];
        }
        __syncthreads();
    }
}

// ------------------------------------------------- P = X@(W1a-W1b)+b1, Q = X@W1b
__global__ __launch_bounds__(256) void pq_kernel(const float* __restrict__ X,
                                                 const float* __restrict__ W1,
                                                 const float* __restrict__ b1,
                                                 float* __restrict__ P,
                                                 float* __restrict__ Q) {
    __shared__ float xrow[16][Dd];
    const int i0 = blockIdx.x * 16;
    for (int t = threadIdx.x; t < 16 * Dd / 4; t += 256)
        ((float4*)&xrow[0][0])[t] = ((const float4*)(X + (size_t)i0 * Dd))[t];
    __syncthreads();
    const int cc = threadIdx.x & 127;
    const int mat = threadIdx.x >> 7;
    float acc[16];
#pragma unroll
    for (int r = 0; r < 16; r++) acc[r] = 0.f;
    for (int d = 0; d < Dd; d++) {
        float w;
        if (mat == 0) w = W1[d * 128 + cc] - W1[(128 + d) * 128 + cc];
        else          w = W1[(128 + d) * 128 + cc];
#pragma unroll
        for (int r = 0; r < 16; r++) acc[r] = fmaf(xrow[r][d], w, acc[r]);
    }
    if (mat == 0) {
        const float b = b1[cc];
#pragma unroll
        for (int r = 0; r < 16; r++) P[(size_t)(i0 + r) * 128 + cc] = acc[r] + b;
    } else {
#pragma unroll
        for (int r = 0; r < 16; r++) Q[(size_t)(i0 + r) * 128 + cc] = acc[r];
    }
}

// ------------------------------------------- h1 = relu(P + max_k Q[idx]) ----
__global__ __launch_bounds__(128) void h1_kernel(const float* __restrict__ P,
                                                 const float* __restrict__ Q,
                                                 const int* __restrict__ idx,
                                                 float* __restrict__ h1) {
    const int i = blockIdx.x;
    const int c = threadIdx.x;
    __shared__ int jb[Kk];
    if (threadIdx.x < Kk) jb[threadIdx.x] = idx[(size_t)i * Kk + threadIdx.x];
    __syncthreads();
    float m = -INFINITY;
#pragma unroll
    for (int k = 0; k < Kk; k++) m = fmaxf(m, Q[(size_t)jb[k] * 128 + c]);
    h1[(size_t)i * 128 + c] = fmaxf(P[(size_t)i * 128 + c] + m, 0.f);
}

// --------------------------- P2 = h1@(W2a-W2b)+b2, Q2 = h1@W2b (C=10) -------
__global__ __launch_bounds__(256) void pq2_kernel(const float* __restrict__ h1,
                                                  const float* __restrict__ W2,
                                                  const float* __restrict__ b2,
                                                  float* __restrict__ P2,
                                                  float* __restrict__ Q2) {
    __shared__ float w2s[2560];        // 256 x 10, linear
    __shared__ float h1s[16][132];
    const int i0 = blockIdx.x * 16;
    for (int t = threadIdx.x; t < 640; t += 256)
        ((float4*)w2s)[t] = ((const float4*)W2)[t];
    {
        const int r = threadIdx.x >> 4, q = (threadIdx.x & 15) * 8;
        *(float4*)&h1s[r][q]     = *(const float4*)(h1 + (size_t)(i0 + r) * 128 + q);
        *(float4*)&h1s[r][q + 4] = *(const float4*)(h1 + (size_t)(i0 + r) * 128 + q + 4);
    }
    __syncthreads();
    const int il = threadIdx.x >> 4, c = threadIdx.x & 15;
    if (c >= 10) return;
    float pa = 0.f, pb = 0.f;
#pragma unroll 4
    for (int d = 0; d < Dd; d++) {
        const float h = h1s[il][d];
        const float wa = w2s[d * 10 + c];
        const float wb = w2s[(128 + d) * 10 + c];
        pa = fmaf(h, wa - wb, pa);
        pb = fmaf(h, wb, pb);
    }
    P2[(size_t)(i0 + il) * 10 + c] = pa + b2[c];
    Q2[(size_t)(i0 + il) * 10 + c] = pb;
}

// ---------------------------------- out = P2 + max_k Q2[idx] (no relu) ------
__global__ __launch_bounds__(256) void out_kernel(const float* __restrict__ P2,
                                                  const float* __restrict__ Q2,
                                                  const int* __restrict__ idx,
                                                  float* __restrict__ out) {
    const int g = blockIdx.x * 256 + threadIdx.x;
    const int i = g >> 4;
    const int c = g & 15;
    if (c >= 10) return;
    const int* jr = idx + (size_t)i * Kk;
    float m = -INFINITY;
#pragma unroll
    for (int k = 0; k < Kk; k++) m = fmaxf(m, Q2[(size_t)jr[k] * 10 + c]);
    out[(size_t)i * 10 + c] = P2[(size_t)i * 10 + c] + m;
}

extern "C" void kernel_launch(void* const* d_in, const int* in_sizes, int n_in,
                              void* d_out, int out_size, void* d_ws, size_t ws_size,
                              hipStream_t stream) {
    const float* X  = (const float*)d_in[0];
    const float* W1 = (const float*)d_in[1];
    const float* b1 = (const float*)d_in[2];
    const float* W2 = (const float*)d_in[3];
    const float* b2 = (const float*)d_in[4];
    float* out = (float*)d_out;

    char* ws = (char*)d_ws;
    float* sqn     = (float*)(ws + 0);            // 64 KB + 256 B pad (prefetch overrun)
    float* thrA    = (float*)(ws + 73728);        // 64 KB
    int*   flagCnt = (int*)(ws + 139264);         // 128 B
    int*   flagRows= (int*)(ws + 139392);         // 64 KB
    int*   idx     = (int*)(ws + 262144);         // 2 MB
    u16*   Xhi     = (u16*)(ws + 2359296);        // (16384+32)*256 B = 4.2 MB (padded)
    float* P       = (float*)(ws + 6561792);      // 8 MB
    float* Q       = P + (size_t)Nn * 128;        // 8 MB
    float* h1      = Q + (size_t)Nn * 128;        // 8 MB
    float* P2      = h1 + (size_t)Nn * 128;       // 640 KB
    float* Q2      = P2 + (size_t)Nn * 10;        // 640 KB
    // cand (12 MB) + candCnt alias P/Q (consumed before pq writes them);
    // cleanup scratch (16 MB) aliases the same span (cand dead by then).
    u16* cand    = (u16*)P;
    int* candCnt = (int*)((char*)P + 13631488);   // 512 KB
    float* cleanupScratch = P;                    // 256 blocks x 64 KB = 16 MB

    prep_kernel<<<Nn / 4, 256, 0, stream>>>(X, Xhi, sqn, thrA, flagCnt);
    knn_filter<<<256 * JSPLIT, 256, 0, stream>>>(Xhi, sqn, thrA, cand, candCnt);
    knn_exact<<<Nn / 4, 256, 0, stream>>>(X, sqn, thrA, cand, candCnt, idx, flagCnt, flagRows);
    knn_cleanup<<<256, 256, 0, stream>>>(X, sqn, flagCnt, flagRows, cleanupScratch, idx);
    pq_kernel<<<Nn / 16, 256, 0, stream>>>(X, W1, b1, P, Q);
    h1_kernel<<<Nn, 128, 0, stream>>>(P, Q, idx, h1);
    pq2_kernel<<<Nn / 16, 256, 0, stream>>>(h1, W2, b2, P2, Q2);
    out_kernel<<<Nn * 16 / 256, 256, 0, stream>>>(P2, Q2, idx, out);
}

// Round 11
// 744.660 us; speedup vs baseline: 1.2409x; 1.2409x over previous
//
#include <hip/hip_runtime.h>
#include <math.h>

#define Nn 16384
#define Dd 128
#define Kk 32
#define JSPLIT 8
#define JCH (Nn / JSPLIT)     // 2048 j per chunk
#define NG (JCH / 16)         // 128 groups of 16 j per chunk
#define CAP 48                // cand slots per (row, chunk); mean ~16
#define MAXSLOT 6             // ceil(JSPLIT*CAP/64)
#define BAND 0.4f             // 2x bound on hi-bf16 approx rv error (validated r4-r10)
#define ZQ 2.4176f            // Phi^-1(1/128): expected ~128 candidates/row total

typedef unsigned short u16;
typedef short short8 __attribute__((ext_vector_type(8)));
typedef float f32x4 __attribute__((ext_vector_type(4)));

__device__ __forceinline__ u16 f2bf(float x) {
    unsigned u = __float_as_uint(x);
    unsigned r = u + 0x7FFFu + ((u >> 16) & 1u);   // RN-even
    return (u16)(r >> 16);
}

// --------------- prep: bf16 convert + sqn + analytic threshold + flag=0 ----
__global__ __launch_bounds__(256) void prep_kernel(const float* __restrict__ X,
                                                   u16* __restrict__ Xhi,
                                                   float* __restrict__ sqn,
                                                   float* __restrict__ thrA,
                                                   int* __restrict__ flagCnt) {
    const int i = blockIdx.x * 4 + (threadIdx.x >> 6);
    const int lane = threadIdx.x & 63;
    const float2 v = *(const float2*)(X + (size_t)i * Dd + lane * 2);
    const unsigned pack = ((unsigned)f2bf(v.y) << 16) | (unsigned)f2bf(v.x);
    *(unsigned*)(Xhi + (size_t)i * Dd + lane * 2) = pack;
    float s = fmaf(v.x, v.x, v.y * v.y);
#pragma unroll
    for (int o = 32; o > 0; o >>= 1) s += __shfl_down(s, o);
    if (lane == 0) {
        sqn[i] = s;
        // rv = sqn_j - 2 xi.xj ~ N(128, 256 + 4*sqn_i); keep rv < thr
        thrA[i] = 128.0f - ZQ * sqrtf(256.0f + 4.0f * s);
    }
    if (blockIdx.x == 0 && threadIdx.x == 0) *flagCnt = 0;
}

// ----------------------------------------------------------- knn filter ----
// 512 blocks (64 i-tiles of 256 rows x 8 j-chunks) x 256 threads, LB(256,2).
// Wave owns 64 i-rows: aF[4][4] = 64 VGPRs resident, 16 MFMAs per 16-j group
// -> issue work (~280 cyc) comparable to L2 latency, so load stalls are
// bounded even if the compiler won't hold the B ping-pong. Static analytic
// thresholds (r9/r10-validated); accepts -> LDS lists; quad-replicated
// register counters (r8-validated). Zero barriers.
__global__ __launch_bounds__(256, 2) void knn_filter(const u16* __restrict__ Xhi,
                                                     const float* __restrict__ sqn,
                                                     const float* __restrict__ thrA,
                                                     u16* __restrict__ cand,
                                                     int* __restrict__ candCnt) {
    __shared__ u16 listS[256][CAP];   // 24 KB
    __shared__ int cntS[256];

    const int tid = threadIdx.x;
    const int wave = tid >> 6, lane = tid & 63;
    const int quad = lane >> 4, n16 = lane & 15;
    const int itile = blockIdx.x >> 3, chunk = blockIdx.x & 7;
    const int ibase = itile * 256;
    const int wbase = ibase + wave * 64;
    const int jch0 = chunk * JCH;

    short8 aF[4][4];
#pragma unroll
    for (int is = 0; is < 4; is++) {
        const u16* arow = Xhi + (size_t)(wbase + is * 16 + n16) * Dd + quad * 8;
#pragma unroll
        for (int ks = 0; ks < 4; ks++) aF[is][ks] = *(const short8*)(arow + ks * 32);
    }
    float rvThr[16];
    int cntReg[16];
#pragma unroll
    for (int is = 0; is < 4; is++)
#pragma unroll
        for (int r = 0; r < 4; r++) {
            rvThr[is * 4 + r] = thrA[wbase + is * 16 + quad * 4 + r];
            cntReg[is * 4 + r] = 0;
        }

    const u16* bbase = Xhi + (size_t)(jch0 + n16) * Dd + quad * 8;
    short8 bb[2][4];
    float sj[2];
#pragma unroll
    for (int ks = 0; ks < 4; ks++) bb[0][ks] = *(const short8*)(bbase + ks * 32);
    sj[0] = sqn[jch0 + n16];
#pragma unroll
    for (int ks = 0; ks < 4; ks++) bb[1][ks] = *(const short8*)(bbase + 16 * Dd + ks * 32);
    sj[1] = sqn[jch0 + 16 + n16];

#define PROC(p, gg)                                                            \
    {                                                                          \
        f32x4 acc[4];                                                          \
        acc[0] = (f32x4){0.f, 0.f, 0.f, 0.f}; acc[1] = acc[0];                 \
        acc[2] = acc[0]; acc[3] = acc[0];                                      \
        _Pragma("unroll")                                                      \
        for (int ks = 0; ks < 4; ks++) {                                       \
            acc[0] = __builtin_amdgcn_mfma_f32_16x16x32_bf16(aF[0][ks], bb[p][ks], acc[0], 0, 0, 0); \
            acc[1] = __builtin_amdgcn_mfma_f32_16x16x32_bf16(aF[1][ks], bb[p][ks], acc[1], 0, 0, 0); \
            acc[2] = __builtin_amdgcn_mfma_f32_16x16x32_bf16(aF[2][ks], bb[p][ks], acc[2], 0, 0, 0); \
            acc[3] = __builtin_amdgcn_mfma_f32_16x16x32_bf16(aF[3][ks], bb[p][ks], acc[3], 0, 0, 0); \
        }                                                                      \
        const float sjc = sj[p];                                               \
        {   /* unconditional distance-2 prefetch: Xhi/sqn padded past end */   \
            const u16* nb = bbase + (size_t)((gg) + 2) * 16 * Dd;              \
            bb[p][0] = *(const short8*)(nb);                                   \
            bb[p][1] = *(const short8*)(nb + 32);                              \
            bb[p][2] = *(const short8*)(nb + 64);                              \
            bb[p][3] = *(const short8*)(nb + 96);                              \
            sj[p] = sqn[jch0 + ((gg) + 2) * 16 + n16];                         \
        }                                                                      \
        const int jj = jch0 + (gg) * 16 + n16;                                 \
        _Pragma("unroll")                                                      \
        for (int is = 0; is < 4; is++) {                                       \
            _Pragma("unroll")                                                  \
            for (int r = 0; r < 4; r++) {                                      \
                const float rv = fmaf(-2.f, acc[is][r], sjc);                  \
                const unsigned long long mr = __ballot(rv < rvThr[is * 4 + r]); \
                const unsigned qm = (unsigned)((mr >> (quad * 16)) & 0xFFFFull); \
                if (qm) {                                                      \
                    if ((qm >> n16) & 1u) {                                    \
                        const int pos = cntReg[is * 4 + r] + __popc(qm & ((1u << n16) - 1u)); \
                        if (pos < CAP)                                         \
                            listS[wave * 64 + is * 16 + quad * 4 + r][pos] = (u16)jj; \
                    }                                                          \
                    cntReg[is * 4 + r] += __popc(qm);                          \
                }                                                              \
            }                                                                  \
        }                                                                      \
    }

    for (int g = 0; g < NG; g += 2) {
        PROC(0, g)
        PROC(1, g + 1)
    }
#undef PROC

    // counts -> LDS (quad leader), then per-wave flush of its own 64 rows
    if (n16 == 0) {
#pragma unroll
        for (int is = 0; is < 4; is++)
#pragma unroll
            for (int r = 0; r < 4; r++)
                cntS[wave * 64 + is * 16 + quad * 4 + r] = cntReg[is * 4 + r];
    }
    for (int rl = 0; rl < 64; rl++) {
        const int row = wave * 64 + rl;
        const int n = cntS[row];            // same-wave LDS: no barrier needed
        const int gi = ibase + row;
        if (lane == 0) candCnt[(size_t)gi * JSPLIT + chunk] = n;  // raw (overflow signal)
        if (lane < min(n, CAP))
            cand[((size_t)gi * JSPLIT + chunk) * CAP + lane] = listS[row][lane];
    }
}

// ----------------------------------------------------------- knn exact -----
// 4096 blocks x 256 (wave = one row). Exact fp32 re-rank of the candidate
// union; slot count DYNAMIC (typically 2 of 6). Verifies sufficiency
// (>=32 exact below thr-BAND, no overflow); failures -> knn_cleanup.
__global__ __launch_bounds__(256) void knn_exact(const float* __restrict__ X,
                                                 const float* __restrict__ sqn,
                                                 const float* __restrict__ thrA,
                                                 const u16* __restrict__ cand,
                                                 const int* __restrict__ candCnt,
                                                 int* __restrict__ idx_out,
                                                 int* __restrict__ flagCnt,
                                                 int* __restrict__ flagRows) {
    __shared__ float xiS[4][Dd];
    const int wave = threadIdx.x >> 6, lane = threadIdx.x & 63;
    const int i = blockIdx.x * 4 + wave;
    *(float2*)&xiS[wave][lane * 2] = *(const float2*)(X + (size_t)i * Dd + lane * 2);
    int pre[JSPLIT];
    bool over = false;
    int M = 0;
#pragma unroll
    for (int k = 0; k < JSPLIT; k++) {
        int c = candCnt[(size_t)i * JSPLIT + k];
        over = over || (c > CAP);
        pre[k] = M;
        M += min(c, CAP);
    }
    const float rvT = thrA[i];
    const int nslots = (M + 63) >> 6;   // wave-uniform

    float rv[MAXSLOT];
    int jd[MAXSLOT];
#pragma unroll
    for (int s = 0; s < MAXSLOT; s++) { rv[s] = INFINITY; jd[s] = -1; }
    for (int s = 0; s < nslots; s++) {
        const int slot = lane + 64 * s;
        if (slot < M) {
            int k = 0;
#pragma unroll
            for (int q = 1; q < JSPLIT; q++) if (slot >= pre[q]) k = q;
            const int jj = cand[((size_t)i * JSPLIT + k) * CAP + (slot - pre[k])];
            const float* xj = X + (size_t)jj * Dd;
            float s0 = 0.f, s1 = 0.f, s2 = 0.f, s3 = 0.f;
#pragma unroll
            for (int d = 0; d < Dd; d += 4) {
                const float4 a = *(const float4*)&xiS[wave][d];
                const float4 b = *(const float4*)(xj + d);
                s0 = fmaf(a.x, b.x, s0); s1 = fmaf(a.y, b.y, s1);
                s2 = fmaf(a.z, b.z, s2); s3 = fmaf(a.w, b.w, s3);
            }
            rv[s] = fmaf(-2.f, (s0 + s1) + (s2 + s3), sqn[jj]);
            jd[s] = jj;
        }
    }
    int good = 0;
    for (int s = 0; s < nslots; s++) good += __popcll(__ballot(rv[s] < rvT - BAND));
    if (over || good < Kk) {   // insufficient evidence -> exact cleanup path
        if (lane == 0) { const int f = atomicAdd(flagCnt, 1); flagRows[f] = i; }
        return;
    }
    int rk[MAXSLOT] = {0, 0, 0, 0, 0, 0};
    for (int s2 = 0; s2 < 64; s2++) {
        float ov[MAXSLOT];
        for (int s = 0; s < nslots; s++) ov[s] = __shfl(rv[s], s2);
        for (int s = 0; s < nslots; s++) {
            const int myid = lane + 64 * s;
            for (int t = 0; t < nslots; t++)
                rk[s] += (ov[t] < rv[s] || (ov[t] == rv[s] && s2 + 64 * t < myid));
        }
    }
    for (int s = 0; s < nslots; s++)
        if (jd[s] >= 0 && rk[s] < Kk) idx_out[(size_t)i * Kk + rk[s]] = jd[s];
}

// ----------------------------------------------------------- knn cleanup ---
// Exact fp32 full-scan top-32 for flagged rows (expected: none).
__global__ __launch_bounds__(256) void knn_cleanup(const float* __restrict__ X,
                                                   const float* __restrict__ sqn,
                                                   const int* __restrict__ flagCnt,
                                                   const int* __restrict__ flagRows,
                                                   float* __restrict__ scratch,
                                                   int* __restrict__ idx_out) {
    __shared__ float xi[Dd];
    __shared__ int cntS;
    __shared__ float lv[256];
    __shared__ int lj[256];
    const int tid = threadIdx.x;
    const int lane = tid & 63;
    const int F = *flagCnt;
    float* rvS = scratch + (size_t)blockIdx.x * Nn;
    for (int f = blockIdx.x; f < F; f += gridDim.x) {
        const int i = flagRows[f];
        __syncthreads();
        if (tid < Dd) xi[tid] = X[(size_t)i * Dd + tid];
        __syncthreads();
        for (int j = tid; j < Nn; j += 256) {
            const float* xj = X + (size_t)j * Dd;
            float s0 = 0.f, s1 = 0.f, s2 = 0.f, s3 = 0.f;
#pragma unroll
            for (int d = 0; d < Dd; d += 4) {
                const float4 a = *(const float4*)&xi[d];
                const float4 b = *(const float4*)(xj + d);
                s0 = fmaf(a.x, b.x, s0); s1 = fmaf(a.y, b.y, s1);
                s2 = fmaf(a.z, b.z, s2); s3 = fmaf(a.w, b.w, s3);
            }
            rvS[j] = fmaf(-2.f, (s0 + s1) + (s2 + s3), sqn[j]);
        }
        __syncthreads();
        float lo = -1.0e9f, hi = 1.0e9f, T = 1.0e9f;
        for (int it = 0; it < 48; it++) {
            const float mid = 0.5f * (lo + hi);
            int local = 0;
            for (int j = tid; j < Nn; j += 256) local += (rvS[j] < mid) ? 1 : 0;
#pragma unroll
            for (int o = 32; o > 0; o >>= 1) local += __shfl_down(local, o);
            __syncthreads();
            if (tid == 0) cntS = 0;
            __syncthreads();
            if (lane == 0) atomicAdd(&cntS, local);
            __syncthreads();
            const int c = cntS;
            if (c < Kk) lo = mid;
            else if (c > 200) hi = mid;
            else { T = mid; break; }
        }
        if (T == 1.0e9f) T = hi;
        __syncthreads();
        if (tid == 0) cntS = 0;
        __syncthreads();
        for (int j = tid; j < Nn; j += 256) {
            if (rvS[j] < T) {
                const int p = atomicAdd(&cntS, 1);
                if (p < 256) { lv[p] = rvS[j]; lj[p] = j; }
            }
        }
        __syncthreads();
        const int n = min(cntS, 256);
        if (tid < 64) {
            float v[4]; int jjj[4]; int rk2[4] = {0, 0, 0, 0};
#pragma unroll
            for (int s = 0; s < 4; s++) {
                const int sl = lane + 64 * s;
                v[s] = (sl < n) ? lv[sl] : INFINITY;
                jjj[s] = (sl < n) ? lj[sl] : -1;
            }
            for (int s2 = 0; s2 < 64; s2++) {
                const float o0 = __shfl(v[0], s2), o1 = __shfl(v[1], s2);
                const float o2 = __shfl(v[2], s2), o3 = __shfl(v[3], s2);
#pragma unroll
                for (int s = 0; s < 4; s++) {
                    const int myid = lane + 64 * s;
                    rk2[s] += (o0 < v[s] || (o0 == v[s] && s2 < myid));
                    rk2[s] += (o1 < v[s] || (o1 == v[s] && s2 + 64 < myid));
                    rk2[s] += (o2 < v[s] || (o2 == v[s] && s2 + 128 < myid));
                    rk2[s] += (o3 < v[s] || (o3 == v[s] && s2 + 192 < myid));
                }
            }
#pragma unroll
            for (int s = 0; s < 4; s++)
                if (jjj[s] >= 0 && rk2[s] < Kk) idx_out[(size_t)i * Kk + rk2[s]] = jjj[s];
        }
        __syncthreads();
    }
}

// ------------------------------------------------- P = X@(W1a-W1b)+b1, Q = X@W1b
__global__ __launch_bounds__(256) void pq_kernel(const float* __restrict__ X,
                                                 const float* __restrict__ W1,
                                                 const float* __restrict__ b1,
                                                 float* __restrict__ P,
                                                 float* __restrict__ Q) {
    __shared__ float xrow[16][Dd];
    const int i0 = blockIdx.x * 16;
    for (int t = threadIdx.x; t < 16 * Dd / 4; t += 256)
        ((float4*)&xrow[0][0])[t] = ((const float4*)(X + (size_t)i0 * Dd))[t];
    __syncthreads();
    const int cc = threadIdx.x & 127;
    const int mat = threadIdx.x >> 7;
    float acc[16];
#pragma unroll
    for (int r = 0; r < 16; r++) acc[r] = 0.f;
    for (int d = 0; d < Dd; d++) {
        float w;
        if (mat == 0) w = W1[d * 128 + cc] - W1[(128 + d) * 128 + cc];
        else          w = W1[(128 + d) * 128 + cc];
#pragma unroll
        for (int r = 0; r < 16; r++) acc[r] = fmaf(xrow[r][d], w, acc[r]);
    }
    if (mat == 0) {
        const float b = b1[cc];
#pragma unroll
        for (int r = 0; r < 16; r++) P[(size_t)(i0 + r) * 128 + cc] = acc[r] + b;
    } else {
#pragma unroll
        for (int r = 0; r < 16; r++) Q[(size_t)(i0 + r) * 128 + cc] = acc[r];
    }
}

// ------------------------------------------- h1 = relu(P + max_k Q[idx]) ----
__global__ __launch_bounds__(128) void h1_kernel(const float* __restrict__ P,
                                                 const float* __restrict__ Q,
                                                 const int* __restrict__ idx,
                                                 float* __restrict__ h1) {
    const int i = blockIdx.x;
    const int c = threadIdx.x;
    __shared__ int jb[Kk];
    if (threadIdx.x < Kk) jb[threadIdx.x] = idx[(size_t)i * Kk + threadIdx.x];
    __syncthreads();
    float m = -INFINITY;
#pragma unroll
    for (int k = 0; k < Kk; k++) m = fmaxf(m, Q[(size_t)jb[k] * 128 + c]);
    h1[(size_t)i * 128 + c] = fmaxf(P[(size_t)i * 128 + c] + m, 0.f);
}

// --------------------------- P2 = h1@(W2a-W2b)+b2, Q2 = h1@W2b (C=10) -------
__global__ __launch_bounds__(256) void pq2_kernel(const float* __restrict__ h1,
                                                  const float* __restrict__ W2,
                                                  const float* __restrict__ b2,
                                                  float* __restrict__ P2,
                                                  float* __restrict__ Q2) {
    __shared__ float w2s[2560];        // 256 x 10, linear
    __shared__ float h1s[16][132];
    const int i0 = blockIdx.x * 16;
    for (int t = threadIdx.x; t < 640; t += 256)
        ((float4*)w2s)[t] = ((const float4*)W2)[t];
    {
        const int r = threadIdx.x >> 4, q = (threadIdx.x & 15) * 8;
        *(float4*)&h1s[r][q]     = *(const float4*)(h1 + (size_t)(i0 + r) * 128 + q);
        *(float4*)&h1s[r][q + 4] = *(const float4*)(h1 + (size_t)(i0 + r) * 128 + q + 4);
    }
    __syncthreads();
    const int il = threadIdx.x >> 4, c = threadIdx.x & 15;
    if (c >= 10) return;
    float pa = 0.f, pb = 0.f;
#pragma unroll 4
    for (int d = 0; d < Dd; d++) {
        const float h = h1s[il][d];
        const float wa = w2s[d * 10 + c];
        const float wb = w2s[(128 + d) * 10 + c];
        pa = fmaf(h, wa - wb, pa);
        pb = fmaf(h, wb, pb);
    }
    P2[(size_t)(i0 + il) * 10 + c] = pa + b2[c];
    Q2[(size_t)(i0 + il) * 10 + c] = pb;
}

// ---------------------------------- out = P2 + max_k Q2[idx] (no relu) ------
__global__ __launch_bounds__(256) void out_kernel(const float* __restrict__ P2,
                                                  const float* __restrict__ Q2,
                                                  const int* __restrict__ idx,
                                                  float* __restrict__ out) {
    const int g = blockIdx.x * 256 + threadIdx.x;
    const int i = g >> 4;
    const int c = g & 15;
    if (c >= 10) return;
    const int* jr = idx + (size_t)i * Kk;
    float m = -INFINITY;
#pragma unroll
    for (int k = 0; k < Kk; k++) m = fmaxf(m, Q2[(size_t)jr[k] * 10 + c]);
    out[(size_t)i * 10 + c] = P2[(size_t)i * 10 + c] + m;
}

extern "C" void kernel_launch(void* const* d_in, const int* in_sizes, int n_in,
                              void* d_out, int out_size, void* d_ws, size_t ws_size,
                              hipStream_t stream) {
    const float* X  = (const float*)d_in[0];
    const float* W1 = (const float*)d_in[1];
    const float* b1 = (const float*)d_in[2];
    const float* W2 = (const float*)d_in[3];
    const float* b2 = (const float*)d_in[4];
    float* out = (float*)d_out;

    char* ws = (char*)d_ws;
    float* sqn     = (float*)(ws + 0);            // 64 KB + pad (prefetch overrun)
    float* thrA    = (float*)(ws + 73728);        // 64 KB
    int*   flagCnt = (int*)(ws + 139264);         // 128 B
    int*   flagRows= (int*)(ws + 139392);         // 64 KB
    int*   idx     = (int*)(ws + 262144);         // 2 MB
    u16*   Xhi     = (u16*)(ws + 2359296);        // (16384+32)*256 B (padded)
    float* P       = (float*)(ws + 6561792);      // 8 MB
    float* Q       = P + (size_t)Nn * 128;        // 8 MB
    float* h1      = Q + (size_t)Nn * 128;        // 8 MB
    float* P2      = h1 + (size_t)Nn * 128;       // 640 KB
    float* Q2      = P2 + (size_t)Nn * 10;        // 640 KB
    // cand (12.6 MB) + candCnt alias P/Q (consumed before pq writes them);
    // cleanup scratch (16 MB) aliases the same span (cand dead by then).
    u16* cand    = (u16*)P;
    int* candCnt = (int*)((char*)P + 13631488);   // 512 KB
    float* cleanupScratch = P;                    // 256 blocks x 64 KB = 16 MB

    prep_kernel<<<Nn / 4, 256, 0, stream>>>(X, Xhi, sqn, thrA, flagCnt);
    knn_filter<<<64 * JSPLIT, 256, 0, stream>>>(Xhi, sqn, thrA, cand, candCnt);
    knn_exact<<<Nn / 4, 256, 0, stream>>>(X, sqn, thrA, cand, candCnt, idx, flagCnt, flagRows);
    knn_cleanup<<<256, 256, 0, stream>>>(X, sqn, flagCnt, flagRows, cleanupScratch, idx);
    pq_kernel<<<Nn / 16, 256, 0, stream>>>(X, W1, b1, P, Q);
    h1_kernel<<<Nn, 128, 0, stream>>>(P, Q, idx, h1);
    pq2_kernel<<<Nn / 16, 256, 0, stream>>>(h1, W2, b2, P2, Q2);
    out_kernel<<<Nn * 16 / 256, 256, 0, stream>>>(P2, Q2, idx, out);
}

// Round 12
// 411.548 us; speedup vs baseline: 2.2454x; 1.8094x over previous
//
#include <hip/hip_runtime.h>
#include <math.h>

#define Nn 16384
#define Dd 128
#define Kk 32
#define JSPLIT 8
#define JCH (Nn / JSPLIT)     // 2048 j per chunk
#define NG (JCH / 16)         // 128 groups of 16 j per chunk
#define CAP 48                // cand slots per (row, chunk); mean ~16
#define MAXSLOT 3             // exact-pass capacity 192 (mean M=128, 6-sigma)
#define BAND 0.4f             // 2x bound on hi-bf16 approx rv error (validated r4-r11)
#define ZQ 2.4176f            // Phi^-1(1/128): expected ~128 candidates/row total

typedef unsigned short u16;
typedef short short8 __attribute__((ext_vector_type(8)));
typedef float f32x4 __attribute__((ext_vector_type(4)));

__device__ __forceinline__ u16 f2bf(float x) {
    unsigned u = __float_as_uint(x);
    unsigned r = u + 0x7FFFu + ((u >> 16) & 1u);   // RN-even
    return (u16)(r >> 16);
}

// --------------- prep: bf16 convert + sqn + analytic threshold + flag=0 ----
__global__ __launch_bounds__(256) void prep_kernel(const float* __restrict__ X,
                                                   u16* __restrict__ Xhi,
                                                   float* __restrict__ sqn,
                                                   float* __restrict__ thrA,
                                                   int* __restrict__ flagCnt) {
    const int i = blockIdx.x * 4 + (threadIdx.x >> 6);
    const int lane = threadIdx.x & 63;
    const float2 v = *(const float2*)(X + (size_t)i * Dd + lane * 2);
    const unsigned pack = ((unsigned)f2bf(v.y) << 16) | (unsigned)f2bf(v.x);
    *(unsigned*)(Xhi + (size_t)i * Dd + lane * 2) = pack;
    float s = fmaf(v.x, v.x, v.y * v.y);
#pragma unroll
    for (int o = 32; o > 0; o >>= 1) s += __shfl_down(s, o);
    if (lane == 0) {
        sqn[i] = s;
        // rv = sqn_j - 2 xi.xj ~ N(128, 256 + 4*sqn_i); keep rv < thr
        thrA[i] = 128.0f - ZQ * sqrtf(256.0f + 4.0f * s);
    }
    if (blockIdx.x == 0 && threadIdx.x == 0) *flagCnt = 0;
}

// ----------------------------------------------------------- knn filter ----
// (r11-validated: 512 blocks, wave owns 64 i-rows, aF[4][4] resident,
//  16 MFMAs per 16-j group, static thresholds, LDS lists, zero barriers)
__global__ __launch_bounds__(256, 2) void knn_filter(const u16* __restrict__ Xhi,
                                                     const float* __restrict__ sqn,
                                                     const float* __restrict__ thrA,
                                                     u16* __restrict__ cand,
                                                     int* __restrict__ candCnt) {
    __shared__ u16 listS[256][CAP];   // 24 KB
    __shared__ int cntS[256];

    const int tid = threadIdx.x;
    const int wave = tid >> 6, lane = tid & 63;
    const int quad = lane >> 4, n16 = lane & 15;
    const int itile = blockIdx.x >> 3, chunk = blockIdx.x & 7;
    const int ibase = itile * 256;
    const int wbase = ibase + wave * 64;
    const int jch0 = chunk * JCH;

    short8 aF[4][4];
#pragma unroll
    for (int is = 0; is < 4; is++) {
        const u16* arow = Xhi + (size_t)(wbase + is * 16 + n16) * Dd + quad * 8;
#pragma unroll
        for (int ks = 0; ks < 4; ks++) aF[is][ks] = *(const short8*)(arow + ks * 32);
    }
    float rvThr[16];
    int cntReg[16];
#pragma unroll
    for (int is = 0; is < 4; is++)
#pragma unroll
        for (int r = 0; r < 4; r++) {
            rvThr[is * 4 + r] = thrA[wbase + is * 16 + quad * 4 + r];
            cntReg[is * 4 + r] = 0;
        }

    const u16* bbase = Xhi + (size_t)(jch0 + n16) * Dd + quad * 8;
    short8 bb[2][4];
    float sj[2];
#pragma unroll
    for (int ks = 0; ks < 4; ks++) bb[0][ks] = *(const short8*)(bbase + ks * 32);
    sj[0] = sqn[jch0 + n16];
#pragma unroll
    for (int ks = 0; ks < 4; ks++) bb[1][ks] = *(const short8*)(bbase + 16 * Dd + ks * 32);
    sj[1] = sqn[jch0 + 16 + n16];

#define PROC(p, gg)                                                            \
    {                                                                          \
        f32x4 acc[4];                                                          \
        acc[0] = (f32x4){0.f, 0.f, 0.f, 0.f}; acc[1] = acc[0];                 \
        acc[2] = acc[0]; acc[3] = acc[0];                                      \
        _Pragma("unroll")                                                      \
        for (int ks = 0; ks < 4; ks++) {                                       \
            acc[0] = __builtin_amdgcn_mfma_f32_16x16x32_bf16(aF[0][ks], bb[p][ks], acc[0], 0, 0, 0); \
            acc[1] = __builtin_amdgcn_mfma_f32_16x16x32_bf16(aF[1][ks], bb[p][ks], acc[1], 0, 0, 0); \
            acc[2] = __builtin_amdgcn_mfma_f32_16x16x32_bf16(aF[2][ks], bb[p][ks], acc[2], 0, 0, 0); \
            acc[3] = __builtin_amdgcn_mfma_f32_16x16x32_bf16(aF[3][ks], bb[p][ks], acc[3], 0, 0, 0); \
        }                                                                      \
        const float sjc = sj[p];                                               \
        {   /* unconditional distance-2 prefetch: Xhi/sqn padded past end */   \
            const u16* nb = bbase + (size_t)((gg) + 2) * 16 * Dd;              \
            bb[p][0] = *(const short8*)(nb);                                   \
            bb[p][1] = *(const short8*)(nb + 32);                              \
            bb[p][2] = *(const short8*)(nb + 64);                              \
            bb[p][3] = *(const short8*)(nb + 96);                              \
            sj[p] = sqn[jch0 + ((gg) + 2) * 16 + n16];                         \
        }                                                                      \
        const int jj = jch0 + (gg) * 16 + n16;                                 \
        _Pragma("unroll")                                                      \
        for (int is = 0; is < 4; is++) {                                       \
            _Pragma("unroll")                                                  \
            for (int r = 0; r < 4; r++) {                                      \
                const float rv = fmaf(-2.f, acc[is][r], sjc);                  \
                const unsigned long long mr = __ballot(rv < rvThr[is * 4 + r]); \
                const unsigned qm = (unsigned)((mr >> (quad * 16)) & 0xFFFFull); \
                if (qm) {                                                      \
                    if ((qm >> n16) & 1u) {                                    \
                        const int pos = cntReg[is * 4 + r] + __popc(qm & ((1u << n16) - 1u)); \
                        if (pos < CAP)                                         \
                            listS[wave * 64 + is * 16 + quad * 4 + r][pos] = (u16)jj; \
                    }                                                          \
                    cntReg[is * 4 + r] += __popc(qm);                          \
                }                                                              \
            }                                                                  \
        }                                                                      \
    }

    for (int g = 0; g < NG; g += 2) {
        PROC(0, g)
        PROC(1, g + 1)
    }
#undef PROC

    if (n16 == 0) {
#pragma unroll
        for (int is = 0; is < 4; is++)
#pragma unroll
            for (int r = 0; r < 4; r++)
                cntS[wave * 64 + is * 16 + quad * 4 + r] = cntReg[is * 4 + r];
    }
    for (int rl = 0; rl < 64; rl++) {
        const int row = wave * 64 + rl;
        const int n = cntS[row];            // same-wave LDS: no barrier needed
        const int gi = ibase + row;
        if (lane == 0) candCnt[(size_t)gi * JSPLIT + chunk] = n;  // raw (overflow signal)
        if (lane < min(n, CAP))
            cand[((size_t)gi * JSPLIT + chunk) * CAP + lane] = listS[row][lane];
    }
}

// ----------------------------------------------------------- knn exact -----
// 4096 blocks x 256 (wave = one row). QUAD-SPLIT gather: 4 lanes cooperate on
// each candidate, each lane reads one contiguous 128-B quarter (one cache
// line, L1-resident across its 8 float4 loads) -> every line fetched once
// (r11 layout touched each line 8x and thrashed L1: 8.6 GB L2 traffic).
// Reduction = 2 shfl_xor across quads; slot s keeps cand 64s+16*quad+n16.
// Verifies sufficiency (>=32 exact below thr-BAND, no overflow, M<=192);
// failures -> knn_cleanup.
__global__ __launch_bounds__(256) void knn_exact(const float* __restrict__ X,
                                                 const float* __restrict__ sqn,
                                                 const float* __restrict__ thrA,
                                                 const u16* __restrict__ cand,
                                                 const int* __restrict__ candCnt,
                                                 int* __restrict__ idx_out,
                                                 int* __restrict__ flagCnt,
                                                 int* __restrict__ flagRows) {
    const int wave = threadIdx.x >> 6, lane = threadIdx.x & 63;
    const int quad = lane >> 4, n16 = lane & 15;
    const int i = blockIdx.x * 4 + wave;

    // xi quarter (32 floats) in registers; broadcast within quad
    float4 xi[8];
    {
        const float4* xb = (const float4*)(X + (size_t)i * Dd + quad * 32);
#pragma unroll
        for (int u = 0; u < 8; u++) xi[u] = xb[u];
    }
    int pre[JSPLIT];
    bool over = false;
    int M = 0;
#pragma unroll
    for (int k = 0; k < JSPLIT; k++) {
        int c = candCnt[(size_t)i * JSPLIT + k];
        over = over || (c > CAP);
        pre[k] = M;
        M += min(c, CAP);
    }
    over = over || (M > 64 * MAXSLOT);
    if (over) {
        if (lane == 0) { const int f = atomicAdd(flagCnt, 1); flagRows[f] = i; }
        return;
    }
    const float rvT = thrA[i];

    float rv[MAXSLOT];
    int jd[MAXSLOT];
#pragma unroll
    for (int s = 0; s < MAXSLOT; s++) { rv[s] = INFINITY; jd[s] = -1; }

#pragma unroll
    for (int s = 0; s < MAXSLOT; s++) {
#pragma unroll
        for (int t = 0; t < 4; t++) {
            const int c = s * 64 + t * 16 + n16;
            if (c < M) {   // uniform across the xor-16/32 reduction group
                int k = 0;
#pragma unroll
                for (int q = 1; q < JSPLIT; q++) if (c >= pre[q]) k = q;
                const int jj = cand[((size_t)i * JSPLIT + k) * CAP + (c - pre[k])];
                const float4* xb = (const float4*)(X + (size_t)jj * Dd + quad * 32);
                float s0 = 0.f, s1 = 0.f, s2 = 0.f, s3 = 0.f;
#pragma unroll
                for (int u = 0; u < 8; u++) {
                    const float4 b = xb[u];
                    s0 = fmaf(xi[u].x, b.x, s0); s1 = fmaf(xi[u].y, b.y, s1);
                    s2 = fmaf(xi[u].z, b.z, s2); s3 = fmaf(xi[u].w, b.w, s3);
                }
                float p = (s0 + s1) + (s2 + s3);
                p += __shfl_xor(p, 16);
                p += __shfl_xor(p, 32);
                if (quad == t) { rv[s] = fmaf(-2.f, p, sqn[jj]); jd[s] = jj; }
            }
        }
    }

    int good = 0;
#pragma unroll
    for (int s = 0; s < MAXSLOT; s++) good += __popcll(__ballot(rv[s] < rvT - BAND));
    if (good < Kk) {   // insufficient evidence -> exact cleanup path
        if (lane == 0) { const int f = atomicAdd(flagCnt, 1); flagRows[f] = i; }
        return;
    }
    int rk[MAXSLOT] = {0, 0, 0};
    for (int s2 = 0; s2 < 64; s2++) {
        float ov[MAXSLOT];
#pragma unroll
        for (int s = 0; s < MAXSLOT; s++) ov[s] = __shfl(rv[s], s2);
#pragma unroll
        for (int s = 0; s < MAXSLOT; s++) {
            const int myid = lane + 64 * s;
#pragma unroll
            for (int t = 0; t < MAXSLOT; t++)
                rk[s] += (ov[t] < rv[s] || (ov[t] == rv[s] && s2 + 64 * t < myid)) ? 1 : 0;
        }
    }
#pragma unroll
    for (int s = 0; s < MAXSLOT; s++)
        if (jd[s] >= 0 && rk[s] < Kk) idx_out[(size_t)i * Kk + rk[s]] = jd[s];
}

// ----------------------------------------------------------- knn cleanup ---
// Exact fp32 full-scan top-32 for flagged rows (expected: none).
__global__ __launch_bounds__(256) void knn_cleanup(const float* __restrict__ X,
                                                   const float* __restrict__ sqn,
                                                   const int* __restrict__ flagCnt,
                                                   const int* __restrict__ flagRows,
                                                   float* __restrict__ scratch,
                                                   int* __restrict__ idx_out) {
    __shared__ float xi[Dd];
    __shared__ int cntS;
    __shared__ float lv[256];
    __shared__ int lj[256];
    const int tid = threadIdx.x;
    const int lane = tid & 63;
    const int F = *flagCnt;
    float* rvS = scratch + (size_t)blockIdx.x * Nn;
    for (int f = blockIdx.x; f < F; f += gridDim.x) {
        const int i = flagRows[f];
        __syncthreads();
        if (tid < Dd) xi[tid] = X[(size_t)i * Dd + tid];
        __syncthreads();
        for (int j = tid; j < Nn; j += 256) {
            const float* xj = X + (size_t)j * Dd;
            float s0 = 0.f, s1 = 0.f, s2 = 0.f, s3 = 0.f;
#pragma unroll
            for (int d = 0; d < Dd; d += 4) {
                const float4 a = *(const float4*)&xi[d];
                const float4 b = *(const float4*)(xj + d);
                s0 = fmaf(a.x, b.x, s0); s1 = fmaf(a.y, b.y, s1);
                s2 = fmaf(a.z, b.z, s2); s3 = fmaf(a.w, b.w, s3);
            }
            rvS[j] = fmaf(-2.f, (s0 + s1) + (s2 + s3), sqn[j]);
        }
        __syncthreads();
        float lo = -1.0e9f, hi = 1.0e9f, T = 1.0e9f;
        for (int it = 0; it < 48; it++) {
            const float mid = 0.5f * (lo + hi);
            int local = 0;
            for (int j = tid; j < Nn; j += 256) local += (rvS[j] < mid) ? 1 : 0;
#pragma unroll
            for (int o = 32; o > 0; o >>= 1) local += __shfl_down(local, o);
            __syncthreads();
            if (tid == 0) cntS = 0;
            __syncthreads();
            if (lane == 0) atomicAdd(&cntS, local);
            __syncthreads();
            const int c = cntS;
            if (c < Kk) lo = mid;
            else if (c > 200) hi = mid;
            else { T = mid; break; }
        }
        if (T == 1.0e9f) T = hi;
        __syncthreads();
        if (tid == 0) cntS = 0;
        __syncthreads();
        for (int j = tid; j < Nn; j += 256) {
            if (rvS[j] < T) {
                const int p = atomicAdd(&cntS, 1);
                if (p < 256) { lv[p] = rvS[j]; lj[p] = j; }
            }
        }
        __syncthreads();
        const int n = min(cntS, 256);
        if (tid < 64) {
            float v[4]; int jjj[4]; int rk2[4] = {0, 0, 0, 0};
#pragma unroll
            for (int s = 0; s < 4; s++) {
                const int sl = lane + 64 * s;
                v[s] = (sl < n) ? lv[sl] : INFINITY;
                jjj[s] = (sl < n) ? lj[sl] : -1;
            }
            for (int s2 = 0; s2 < 64; s2++) {
                const float o0 = __shfl(v[0], s2), o1 = __shfl(v[1], s2);
                const float o2 = __shfl(v[2], s2), o3 = __shfl(v[3], s2);
#pragma unroll
                for (int s = 0; s < 4; s++) {
                    const int myid = lane + 64 * s;
                    rk2[s] += (o0 < v[s] || (o0 == v[s] && s2 < myid));
                    rk2[s] += (o1 < v[s] || (o1 == v[s] && s2 + 64 < myid));
                    rk2[s] += (o2 < v[s] || (o2 == v[s] && s2 + 128 < myid));
                    rk2[s] += (o3 < v[s] || (o3 == v[s] && s2 + 192 < myid));
                }
            }
#pragma unroll
            for (int s = 0; s < 4; s++)
                if (jjj[s] >= 0 && rk2[s] < Kk) idx_out[(size_t)i * Kk + rk2[s]] = jjj[s];
        }
        __syncthreads();
    }
}

// ------------------------------------------------- P = X@(W1a-W1b)+b1, Q = X@W1b
__global__ __launch_bounds__(256) void pq_kernel(const float* __restrict__ X,
                                                 const float* __restrict__ W1,
                                                 const float* __restrict__ b1,
                                                 float* __restrict__ P,
                                                 float* __restrict__ Q) {
    __shared__ float xrow[16][Dd];
    const int i0 = blockIdx.x * 16;
    for (int t = threadIdx.x; t < 16 * Dd / 4; t += 256)
        ((float4*)&xrow[0][0])[t] = ((const float4*)(X + (size_t)i0 * Dd))[t];
    __syncthreads();
    const int cc = threadIdx.x & 127;
    const int mat = threadIdx.x >> 7;
    float acc[16];
#pragma unroll
    for (int r = 0; r < 16; r++) acc[r] = 0.f;
    for (int d = 0; d < Dd; d++) {
        float w;
        if (mat == 0) w = W1[d * 128 + cc] - W1[(128 + d) * 128 + cc];
        else          w = W1[(128 + d) * 128 + cc];
#pragma unroll
        for (int r = 0; r < 16; r++) acc[r] = fmaf(xrow[r][d], w, acc[r]);
    }
    if (mat == 0) {
        const float b = b1[cc];
#pragma unroll
        for (int r = 0; r < 16; r++) P[(size_t)(i0 + r) * 128 + cc] = acc[r] + b;
    } else {
#pragma unroll
        for (int r = 0; r < 16; r++) Q[(size_t)(i0 + r) * 128 + cc] = acc[r];
    }
}

// ------------------------------------------- h1 = relu(P + max_k Q[idx]) ----
__global__ __launch_bounds__(128) void h1_kernel(const float* __restrict__ P,
                                                 const float* __restrict__ Q,
                                                 const int* __restrict__ idx,
                                                 float* __restrict__ h1) {
    const int i = blockIdx.x;
    const int c = threadIdx.x;
    __shared__ int jb[Kk];
    if (threadIdx.x < Kk) jb[threadIdx.x] = idx[(size_t)i * Kk + threadIdx.x];
    __syncthreads();
    float m = -INFINITY;
#pragma unroll
    for (int k = 0; k < Kk; k++) m = fmaxf(m, Q[(size_t)jb[k] * 128 + c]);
    h1[(size_t)i * 128 + c] = fmaxf(P[(size_t)i * 128 + c] + m, 0.f);
}

// --------------------------- P2 = h1@(W2a-W2b)+b2, Q2 = h1@W2b (C=10) -------
__global__ __launch_bounds__(256) void pq2_kernel(const float* __restrict__ h1,
                                                  const float* __restrict__ W2,
                                                  const float* __restrict__ b2,
                                                  float* __restrict__ P2,
                                                  float* __restrict__ Q2) {
    __shared__ float w2s[2560];        // 256 x 10, linear
    __shared__ float h1s[16][132];
    const int i0 = blockIdx.x * 16;
    for (int t = threadIdx.x; t < 640; t += 256)
        ((float4*)w2s)[t] = ((const float4*)W2)[t];
    {
        const int r = threadIdx.x >> 4, q = (threadIdx.x & 15) * 8;
        *(float4*)&h1s[r][q]     = *(const float4*)(h1 + (size_t)(i0 + r) * 128 + q);
        *(float4*)&h1s[r][q + 4] = *(const float4*)(h1 + (size_t)(i0 + r) * 128 + q + 4);
    }
    __syncthreads();
    const int il = threadIdx.x >> 4, c = threadIdx.x & 15;
    if (c >= 10) return;
    float pa = 0.f, pb = 0.f;
#pragma unroll 4
    for (int d = 0; d < Dd; d++) {
        const float h = h1s[il][d];
        const float wa = w2s[d * 10 + c];
        const float wb = w2s[(128 + d) * 10 + c];
        pa = fmaf(h, wa - wb, pa);
        pb = fmaf(h, wb, pb);
    }
    P2[(size_t)(i0 + il) * 10 + c] = pa + b2[c];
    Q2[(size_t)(i0 + il) * 10 + c] = pb;
}

// ---------------------------------- out = P2 + max_k Q2[idx] (no relu) ------
__global__ __launch_bounds__(256) void out_kernel(const float* __restrict__ P2,
                                                  const float* __restrict__ Q2,
                                                  const int* __restrict__ idx,
                                                  float* __restrict__ out) {
    const int g = blockIdx.x * 256 + threadIdx.x;
    const int i = g >> 4;
    const int c = g & 15;
    if (c >= 10) return;
    const int* jr = idx + (size_t)i * Kk;
    float m = -INFINITY;
#pragma unroll
    for (int k = 0; k < Kk; k++) m = fmaxf(m, Q2[(size_t)jr[k] * 10 + c]);
    out[(size_t)i * 10 + c] = P2[(size_t)i * 10 + c] + m;
}

extern "C" void kernel_launch(void* const* d_in, const int* in_sizes, int n_in,
                              void* d_out, int out_size, void* d_ws, size_t ws_size,
                              hipStream_t stream) {
    const float* X  = (const float*)d_in[0];
    const float* W1 = (const float*)d_in[1];
    const float* b1 = (const float*)d_in[2];
    const float* W2 = (const float*)d_in[3];
    const float* b2 = (const float*)d_in[4];
    float* out = (float*)d_out;

    char* ws = (char*)d_ws;
    float* sqn     = (float*)(ws + 0);            // 64 KB + pad (prefetch overrun)
    float* thrA    = (float*)(ws + 73728);        // 64 KB
    int*   flagCnt = (int*)(ws + 139264);         // 128 B
    int*   flagRows= (int*)(ws + 139392);         // 64 KB
    int*   idx     = (int*)(ws + 262144);         // 2 MB
    u16*   Xhi     = (u16*)(ws + 2359296);        // (16384+32)*256 B (padded)
    float* P       = (float*)(ws + 6561792);      // 8 MB
    float* Q       = P + (size_t)Nn * 128;        // 8 MB
    float* h1      = Q + (size_t)Nn * 128;        // 8 MB
    float* P2      = h1 + (size_t)Nn * 128;       // 640 KB
    float* Q2      = P2 + (size_t)Nn * 10;        // 640 KB
    // cand (12.6 MB) + candCnt alias P/Q (consumed before pq writes them);
    // cleanup scratch (16 MB) aliases the same span (cand dead by then).
    u16* cand    = (u16*)P;
    int* candCnt = (int*)((char*)P + 13631488);   // 512 KB
    float* cleanupScratch = P;                    // 256 blocks x 64 KB = 16 MB

    prep_kernel<<<Nn / 4, 256, 0, stream>>>(X, Xhi, sqn, thrA, flagCnt);
    knn_filter<<<64 * JSPLIT, 256, 0, stream>>>(Xhi, sqn, thrA, cand, candCnt);
    knn_exact<<<Nn / 4, 256, 0, stream>>>(X, sqn, thrA, cand, candCnt, idx, flagCnt, flagRows);
    knn_cleanup<<<256, 256, 0, stream>>>(X, sqn, flagCnt, flagRows, cleanupScratch, idx);
    pq_kernel<<<Nn / 16, 256, 0, stream>>>(X, W1, b1, P, Q);
    h1_kernel<<<Nn, 128, 0, stream>>>(P, Q, idx, h1);
    pq2_kernel<<<Nn / 16, 256, 0, stream>>>(h1, W2, b2, P2, Q2);
    out_kernel<<<Nn * 16 / 256, 256, 0, stream>>>(P2, Q2, idx, out);
}